// Round 3
// baseline (19147.426 us; speedup 1.0000x reference)
//
#include <hip/hip_runtime.h>

// ---------------------------------------------------------------------------
// Bidirectional GRU encoder (Keras v2, reset_after=True, mask_zero)
// Round 2 fix: DOUBLE-BUFFERED h mirror in the persistent scan (round 2's
// single-buffer version raced: step s+1 writes overlapped step s+1 reads).
// ---------------------------------------------------------------------------

#define T_SEQ 256
#define BATCH 128
#define EMB_D 512
#define UNITS 1024
#define NROWS (BATCH * T_SEQ) /* 32768 */
#define N3U 3072
#define N6U 6144

typedef __attribute__((ext_vector_type(8))) __bf16 bfv8;
typedef __attribute__((ext_vector_type(4))) float f32x4;

__device__ inline unsigned short f2bf(float f) {
  union { float f; unsigned int u; } x; x.f = f;
  unsigned int u = x.u;
  unsigned int r = (u + 0x7fffu + ((u >> 16) & 1u)) >> 16; // RNE
  return (unsigned short)r;
}
__device__ inline float bf2f(unsigned short h) {
  union { unsigned int u; float f; } x; x.u = ((unsigned int)h) << 16;
  return x.f;
}
__device__ inline f32x4 mfma16(bfv8 a, bfv8 b, f32x4 c) {
  return __builtin_amdgcn_mfma_f32_16x16x32_bf16(a, b, c, 0, 0, 0);
}
__device__ inline void gl_lds16(const unsigned short* g, unsigned short* l) {
  __builtin_amdgcn_global_load_lds(
      (const __attribute__((address_space(1))) void*)g,
      (__attribute__((address_space(3))) void*)l, 16, 0, 0);
}

// dst[N][K] (bf16) = src[K][N] (f32), 32x32 LDS-tiled transpose
__global__ __launch_bounds__(256) void k_transpose(const float* __restrict__ src,
                                                   unsigned short* __restrict__ dst,
                                                   int K, int N) {
  __shared__ float tile[32][33];
  int k0 = blockIdx.x * 32, n0 = blockIdx.y * 32;
  int tx = threadIdx.x & 31, ty = threadIdx.x >> 5;
#pragma unroll
  for (int i = 0; i < 4; ++i)
    tile[ty + i * 8][tx] = src[(size_t)(k0 + ty + i * 8) * N + n0 + tx];
  __syncthreads();
#pragma unroll
  for (int i = 0; i < 4; ++i)
    dst[(size_t)(n0 + ty + i * 8) * K + k0 + tx] = f2bf(tile[tx][ty + i * 8]);
}

// Xbf[32768][512] bf16 = emb[tokens[row]]
__global__ __launch_bounds__(256) void k_gather(const int* __restrict__ tokens,
                                                const float* __restrict__ emb,
                                                unsigned short* __restrict__ Xbf) {
  int idx = blockIdx.x * 256 + threadIdx.x; // one float4 per thread
  int row = idx >> 7;
  int c4 = (idx & 127) * 4;
  int tok = tokens[row];
  float4 v = *(const float4*)(emb + (size_t)tok * EMB_D + c4);
  ushort4 p;
  p.x = f2bf(v.x); p.y = f2bf(v.y); p.z = f2bf(v.z); p.w = f2bf(v.w);
  *(ushort4*)(Xbf + (size_t)row * EMB_D + c4) = p;
}

// biasX[6144] = [b_f[0] | b_b[0]],  biasH[6144] = [b_f[1] | b_b[1]]
__global__ __launch_bounds__(256) void k_bias(const float* __restrict__ bf_,
                                              const float* __restrict__ bb_,
                                              float* __restrict__ biasX,
                                              float* __restrict__ biasH) {
  int i = blockIdx.x * 256 + threadIdx.x;
  if (i >= N6U) return;
  if (i < N3U) { biasX[i] = bf_[i];        biasH[i] = bf_[N3U + i]; }
  else         { biasX[i] = bb_[i - N3U];  biasH[i] = bb_[i]; }
}

// C[M][N] = A[M][K](bf16) @ BT[N][K](bf16)^T + bias[N]
// 128x128 tile, 4 waves, BK=32, global_load_lds(16B) staging (m97 structure).
__global__ __launch_bounds__(256) void k_gemm(const unsigned short* __restrict__ A,
                                              const unsigned short* __restrict__ BT,
                                              const float* __restrict__ bias,
                                              void* __restrict__ C,
                                              int M, int N, int K, int out_f32) {
  __shared__ unsigned short As[128 * 32];
  __shared__ unsigned short Bs[128 * 32];
  const int mt = blockIdx.x, nt = blockIdx.y;
  const int tid = threadIdx.x;
  const int wid = tid >> 6, lane = tid & 63;
  const int wm = (wid >> 1) * 64, wn = (wid & 1) * 64;
  const int l15 = lane & 15, lk = (lane >> 4) * 8;

  f32x4 acc[4][4];
#pragma unroll
  for (int i = 0; i < 4; ++i)
#pragma unroll
    for (int j = 0; j < 4; ++j) acc[i][j] = (f32x4){0.f, 0.f, 0.f, 0.f};

  const int r = tid >> 2;          // staging row 0..63
  const int cc = (tid & 3) * 8;    // staging col (elements)
  const unsigned short* ga0 = A + (size_t)(mt * 128 + r) * K + cc;
  const unsigned short* ga1 = ga0 + (size_t)64 * K;
  const unsigned short* gb0 = BT + (size_t)(nt * 128 + r) * K + cc;
  const unsigned short* gb1 = gb0 + (size_t)64 * K;
  unsigned short* lA0 = As + r * 32 + cc;        // byte off = tid*16, wave-linear
  unsigned short* lA1 = As + (64 + r) * 32 + cc;
  unsigned short* lB0 = Bs + r * 32 + cc;
  unsigned short* lB1 = Bs + (64 + r) * 32 + cc;

  for (int k0 = 0; k0 < K; k0 += 32) {
    __syncthreads(); // previous iter's LDS reads complete
    gl_lds16(ga0 + k0, lA0);
    gl_lds16(ga1 + k0, lA1);
    gl_lds16(gb0 + k0, lB0);
    gl_lds16(gb1 + k0, lB1);
    __syncthreads(); // loads landed (vmcnt drained before barrier)
    bfv8 af[4], bfr[4];
#pragma unroll
    for (int i = 0; i < 4; ++i) {
      af[i]  = *(const bfv8*)(As + (wm + i * 16 + l15) * 32 + lk);
      bfr[i] = *(const bfv8*)(Bs + (wn + i * 16 + l15) * 32 + lk);
    }
#pragma unroll
    for (int i = 0; i < 4; ++i)
#pragma unroll
      for (int j = 0; j < 4; ++j) acc[i][j] = mfma16(af[i], bfr[j], acc[i][j]);
  }

#pragma unroll
  for (int j = 0; j < 4; ++j) {
    int col = nt * 128 + wn + j * 16 + l15;
    float bv = bias[col];
#pragma unroll
    for (int i = 0; i < 4; ++i) {
      int row0 = mt * 128 + wm + i * 16 + (lane >> 4) * 4;
#pragma unroll
      for (int q = 0; q < 4; ++q) {
        float v = acc[i][j][q] + bv;
        if (out_f32) ((float*)C)[(size_t)(row0 + q) * N + col] = v;
        else ((unsigned short*)C)[(size_t)(row0 + q) * N + col] = f2bf(v);
      }
    }
  }
}

// ---------------------------------------------------------------------------
// Persistent fused GRU scan. Grid = 256 WGs (1/CU, forced by 96KB LDS):
//   bid = dir*128 + mg*64 + utile.  WG owns 64 batch rows x 16 u-cols, 1 dir.
// Wh slice lives in LDS as Wl[gate][k/8][u][8] (B-fragment = 16B contiguous).
// f32 master h state in 4 VGPRs/lane.  h mirror (bf16) is DOUBLE-BUFFERED:
// step s reads hb[(s&1)^1], writes hb[s&1]; one 64-WG barrier per step keeps
// all WGs in the same step, so reads/writes never touch the same buffer.
// ---------------------------------------------------------------------------
__global__ __launch_bounds__(256) void k_scan(const unsigned short* __restrict__ XP,
                                              const unsigned short* __restrict__ WhT,
                                              const float* __restrict__ biasH,
                                              const int* __restrict__ tokens,
                                              unsigned short* __restrict__ hb0,
                                              unsigned short* __restrict__ hb1,
                                              float* __restrict__ out,
                                              unsigned int* __restrict__ bar) {
  __shared__ unsigned short Wl[3 * 128 * 16 * 8]; // 96 KB
  const int bid = blockIdx.x;
  const int dir = bid >> 7;
  const int mg  = (bid >> 6) & 1;
  const int ut  = bid & 63;
  const int u0 = ut * 16, m0 = mg * 64;
  const int grp = bid >> 6; // 4 groups of 64 WGs

  // stage Wh slice -> LDS (once)
  for (int c = threadIdx.x; c < 6144; c += 256) {
    const int g  = c >> 11;         // gate
    const int kb = (c >> 4) & 127;  // k-block of 8
    const int uu = c & 15;
    *(uint4*)(Wl + (((g << 7) | kb) * 16 + uu) * 8) =
        *(const uint4*)(WhT + (((size_t)(dir * N3U + (g << 10) + u0 + uu)) << 10) + (kb << 3));
  }

  const int lane = threadIdx.x & 63, wid = threadIdx.x >> 6;
  const int l15 = lane & 15, hi = lane >> 4;
  const size_t aoff = ((size_t)(m0 + wid * 16 + l15) << 11) + (dir << 10) + (hi << 3);
  const int u = u0 + l15;
  const float bz  = biasH[dir * N3U + u];
  const float brg = biasH[dir * N3U + 1024 + u];
  const float bhg = biasH[dir * N3U + 2048 + u];
  const int ob = m0 + wid * 16 + (hi << 2); // this lane's 4 output rows: ob..ob+3
  const size_t woff = (dir << 10) + u;

  float hreg[4] = {0.f, 0.f, 0.f, 0.f}; // f32 master state (private to this WG)
  __syncthreads();

  for (int s = 0; s < T_SEQ; ++s) {
    const int t = dir ? (T_SEQ - 1 - s) : s;
    const unsigned short* hrd = (s & 1) ? hb0 : hb1; // h_{s-1}
    unsigned short* hwr       = (s & 1) ? hb1 : hb0; // h_s

    // hoist XP + token loads for this step (hide latency under MFMAs)
    float xz[4], xr[4], xh[4]; int tok[4];
#pragma unroll
    for (int q = 0; q < 4; ++q) {
      const size_t xpo = ((size_t)((ob + q) * T_SEQ + t)) * N6U + dir * N3U + u;
      xz[q] = bf2f(XP[xpo]);
      xr[q] = bf2f(XP[xpo + 1024]);
      xh[q] = bf2f(XP[xpo + 2048]);
      tok[q] = tokens[(ob + q) * T_SEQ + t];
    }

    const unsigned short* ap = hrd + aoff;
    f32x4 az0 = {0.f,0.f,0.f,0.f}, az1 = az0, ar0 = az0, ar1 = az0, ah0 = az0, ah1 = az0;
#pragma unroll 4
    for (int ks = 0; ks < 16; ++ks) { // 64 k-elements per iter (2 k-splits)
      bfv8 a0 = *(const bfv8*)(ap + (ks << 6));
      bfv8 a1 = *(const bfv8*)(ap + (ks << 6) + 32);
      const unsigned short* wp = Wl + (((ks << 3) + hi) * 16 + l15) * 8;
      bfv8 wz0 = *(const bfv8*)(wp);
      bfv8 wr0 = *(const bfv8*)(wp + (1 << 14));
      bfv8 wh0 = *(const bfv8*)(wp + (2 << 14));
      bfv8 wz1 = *(const bfv8*)(wp + 512);            // kb+4
      bfv8 wr1 = *(const bfv8*)(wp + (1 << 14) + 512);
      bfv8 wh1 = *(const bfv8*)(wp + (2 << 14) + 512);
      az0 = mfma16(a0, wz0, az0); ar0 = mfma16(a0, wr0, ar0); ah0 = mfma16(a0, wh0, ah0);
      az1 = mfma16(a1, wz1, az1); ar1 = mfma16(a1, wr1, ar1); ah1 = mfma16(a1, wh1, ah1);
    }
    f32x4 az = az0 + az1, ar = ar0 + ar1, ah = ah0 + ah1;

#pragma unroll
    for (int q = 0; q < 4; ++q) {
      const float z  = 1.f / (1.f + __expf(-(xz[q] + az[q] + bz)));
      const float r  = 1.f / (1.f + __expf(-(xr[q] + ar[q] + brg)));
      const float hh = tanhf(xh[q] + r * (ah[q] + bhg));
      float hn = z * hreg[q] + (1.f - z) * hh;
      if (tok[q] == 0) hn = hreg[q]; // masked step carries state
      hreg[q] = hn;
      hwr[((size_t)(ob + q) << 11) + woff] = f2bf(hn);
      __builtin_nontemporal_store(hn, out + ((size_t)((ob + q) * T_SEQ + t) << 11) + woff);
    }

    if (s + 1 < T_SEQ) {
      __threadfence();   // release: hwr writes visible device-wide
      __syncthreads();
      if (threadIdx.x == 0) {
        __hip_atomic_fetch_add(&bar[grp], 1u, __ATOMIC_RELEASE, __HIP_MEMORY_SCOPE_AGENT);
        const unsigned tgt = (unsigned)(64 * (s + 1)); // monotonic: no reset race
        while (__hip_atomic_load(&bar[grp], __ATOMIC_ACQUIRE, __HIP_MEMORY_SCOPE_AGENT) < tgt)
          __builtin_amdgcn_s_sleep(2);
      }
      __syncthreads();
      __threadfence();   // acquire: invalidate caches before re-reading h
    }
  }
}

extern "C" void kernel_launch(void* const* d_in, const int* in_sizes, int n_in,
                              void* d_out, int out_size, void* d_ws, size_t ws_size,
                              hipStream_t stream) {
  const int* tokens = (const int*)d_in[0];
  const float* emb  = (const float*)d_in[1];
  const float* Wx_f = (const float*)d_in[2];
  const float* Wh_f = (const float*)d_in[3];
  const float* b_f  = (const float*)d_in[4];
  const float* Wx_b = (const float*)d_in[5];
  const float* Wh_b = (const float*)d_in[6];
  const float* b_b  = (const float*)d_in[7];
  const float* fc_W = (const float*)d_in[8];
  const float* fc_b = (const float*)d_in[9];
  float* out = (float*)d_out;

  // workspace layout (~430 MB)
  char* w = (char*)d_ws;
  unsigned short* XP  = (unsigned short*)w; w += (size_t)NROWS * N6U * 2;   // 384 MiB
  unsigned short* Xbf = (unsigned short*)w; w += (size_t)NROWS * EMB_D * 2; // 32 MiB
  unsigned short* WxT = (unsigned short*)w; w += (size_t)N6U * EMB_D * 2;   // 6 MiB
  unsigned short* WhT = (unsigned short*)w; w += (size_t)N6U * UNITS * 2;   // 12 MiB
  unsigned short* fcWT = (unsigned short*)w; w += (size_t)UNITS * 2048 * 2; // 4 MiB
  unsigned short* hb0 = (unsigned short*)w; w += (size_t)BATCH * 2048 * 2;  // 0.5 MiB
  unsigned short* hb1 = (unsigned short*)w; w += (size_t)BATCH * 2048 * 2;  // 0.5 MiB
  float* biasX = (float*)w; w += N6U * 4;
  float* biasH = (float*)w; w += N6U * 4;
  unsigned int* bar = (unsigned int*)w; w += 4 * sizeof(unsigned int);

  hipMemsetAsync((void*)hb0, 0, (size_t)BATCH * 2048 * 2 * 2, stream); // hb0+hb1
  hipMemsetAsync((void*)bar, 0, 4 * sizeof(unsigned int), stream);

  // weight prep (f32 -> bf16, [N][K] layouts)
  k_transpose<<<dim3(EMB_D / 32, N3U / 32), 256, 0, stream>>>(Wx_f, WxT, EMB_D, N3U);
  k_transpose<<<dim3(EMB_D / 32, N3U / 32), 256, 0, stream>>>(Wx_b, WxT + (size_t)N3U * EMB_D, EMB_D, N3U);
  k_transpose<<<dim3(UNITS / 32, N3U / 32), 256, 0, stream>>>(Wh_f, WhT, UNITS, N3U);
  k_transpose<<<dim3(UNITS / 32, N3U / 32), 256, 0, stream>>>(Wh_b, WhT + (size_t)N3U * UNITS, UNITS, N3U);
  k_transpose<<<dim3(2048 / 32, 1024 / 32), 256, 0, stream>>>(fc_W, fcWT, 2048, 1024);
  k_bias<<<24, 256, 0, stream>>>(b_f, b_b, biasX, biasH);
  k_gather<<<(NROWS * 128) / 256, 256, 0, stream>>>(tokens, emb, Xbf);

  // input projections, both dirs: XP[32768][6144] bf16
  k_gemm<<<dim3(NROWS / 128, N6U / 128), 256, 0, stream>>>(Xbf, WxT, biasX, XP, NROWS, N6U, EMB_D, 0);

  // fused persistent bidirectional scan (256 steps inside one kernel)
  k_scan<<<256, 256, 0, stream>>>(XP, WhT, biasH, tokens, hb0, hb1, out, bar);

  // hidden = [h_f|h_b] @ fc_W + fc_b (final state is in hb1: step 255 is odd)
  k_gemm<<<dim3(1, 8), 256, 0, stream>>>(hb1, fcWT, fc_b, out + (size_t)NROWS * 2048, BATCH, UNITS, 2048, 1);
}

// Round 5
// 5866.714 us; speedup vs baseline: 3.2637x; 3.2637x over previous
//
#include <hip/hip_runtime.h>

// ---------------------------------------------------------------------------
// Bidirectional GRU encoder (Keras v2, reset_after=True, mask_zero)
// Round 4: compile fix — __builtin_amdgcn_fence instead of __hip_atomic_fence.
// Barrier design: tid0-only {release fence (wbl2), relaxed add, RELAXED poll,
// acquire fence (inv)} between two __syncthreads. Round 2's all-thread
// acquire-polling caused 74us/step of cache-invalidate thrash.
// ---------------------------------------------------------------------------

#define T_SEQ 256
#define BATCH 128
#define EMB_D 512
#define UNITS 1024
#define NROWS (BATCH * T_SEQ) /* 32768 */
#define N3U 3072
#define N6U 6144

typedef __attribute__((ext_vector_type(8))) __bf16 bfv8;
typedef __attribute__((ext_vector_type(4))) float f32x4;

__device__ inline unsigned short f2bf(float f) {
  union { float f; unsigned int u; } x; x.f = f;
  unsigned int u = x.u;
  unsigned int r = (u + 0x7fffu + ((u >> 16) & 1u)) >> 16; // RNE
  return (unsigned short)r;
}
__device__ inline float bf2f(unsigned short h) {
  union { unsigned int u; float f; } x; x.u = ((unsigned int)h) << 16;
  return x.f;
}
__device__ inline f32x4 mfma16(bfv8 a, bfv8 b, f32x4 c) {
  return __builtin_amdgcn_mfma_f32_16x16x32_bf16(a, b, c, 0, 0, 0);
}
__device__ inline void gl_lds16(const unsigned short* g, unsigned short* l) {
  __builtin_amdgcn_global_load_lds(
      (const __attribute__((address_space(1))) void*)g,
      (__attribute__((address_space(3))) void*)l, 16, 0, 0);
}

// dst[N][K] (bf16) = src[K][N] (f32), 32x32 LDS-tiled transpose
__global__ __launch_bounds__(256) void k_transpose(const float* __restrict__ src,
                                                   unsigned short* __restrict__ dst,
                                                   int K, int N) {
  __shared__ float tile[32][33];
  int k0 = blockIdx.x * 32, n0 = blockIdx.y * 32;
  int tx = threadIdx.x & 31, ty = threadIdx.x >> 5;
#pragma unroll
  for (int i = 0; i < 4; ++i)
    tile[ty + i * 8][tx] = src[(size_t)(k0 + ty + i * 8) * N + n0 + tx];
  __syncthreads();
#pragma unroll
  for (int i = 0; i < 4; ++i)
    dst[(size_t)(n0 + ty + i * 8) * K + k0 + tx] = f2bf(tile[tx][ty + i * 8]);
}

// Xbf[32768][512] bf16 = emb[tokens[row]]
__global__ __launch_bounds__(256) void k_gather(const int* __restrict__ tokens,
                                                const float* __restrict__ emb,
                                                unsigned short* __restrict__ Xbf) {
  int idx = blockIdx.x * 256 + threadIdx.x; // one float4 per thread
  int row = idx >> 7;
  int c4 = (idx & 127) * 4;
  int tok = tokens[row];
  float4 v = *(const float4*)(emb + (size_t)tok * EMB_D + c4);
  ushort4 p;
  p.x = f2bf(v.x); p.y = f2bf(v.y); p.z = f2bf(v.z); p.w = f2bf(v.w);
  *(ushort4*)(Xbf + (size_t)row * EMB_D + c4) = p;
}

// biasX[6144] = [b_f[0] | b_b[0]],  biasH[6144] = [b_f[1] | b_b[1]]
__global__ __launch_bounds__(256) void k_bias(const float* __restrict__ bf_,
                                              const float* __restrict__ bb_,
                                              float* __restrict__ biasX,
                                              float* __restrict__ biasH) {
  int i = blockIdx.x * 256 + threadIdx.x;
  if (i >= N6U) return;
  if (i < N3U) { biasX[i] = bf_[i];        biasH[i] = bf_[N3U + i]; }
  else         { biasX[i] = bb_[i - N3U];  biasH[i] = bb_[i]; }
}

// C[M][N] = A[M][K](bf16) @ BT[N][K](bf16)^T + bias[N]
// 128x128 tile, 4 waves, BK=32, global_load_lds(16B) staging (m97 structure).
__global__ __launch_bounds__(256) void k_gemm(const unsigned short* __restrict__ A,
                                              const unsigned short* __restrict__ BT,
                                              const float* __restrict__ bias,
                                              void* __restrict__ C,
                                              int M, int N, int K, int out_f32) {
  __shared__ unsigned short As[128 * 32];
  __shared__ unsigned short Bs[128 * 32];
  const int mt = blockIdx.x, nt = blockIdx.y;
  const int tid = threadIdx.x;
  const int wid = tid >> 6, lane = tid & 63;
  const int wm = (wid >> 1) * 64, wn = (wid & 1) * 64;
  const int l15 = lane & 15, lk = (lane >> 4) * 8;

  f32x4 acc[4][4];
#pragma unroll
  for (int i = 0; i < 4; ++i)
#pragma unroll
    for (int j = 0; j < 4; ++j) acc[i][j] = (f32x4){0.f, 0.f, 0.f, 0.f};

  const int r = tid >> 2;          // staging row 0..63
  const int cc = (tid & 3) * 8;    // staging col (elements)
  const unsigned short* ga0 = A + (size_t)(mt * 128 + r) * K + cc;
  const unsigned short* ga1 = ga0 + (size_t)64 * K;
  const unsigned short* gb0 = BT + (size_t)(nt * 128 + r) * K + cc;
  const unsigned short* gb1 = gb0 + (size_t)64 * K;
  unsigned short* lA0 = As + r * 32 + cc;        // byte off = tid*16, wave-linear
  unsigned short* lA1 = As + (64 + r) * 32 + cc;
  unsigned short* lB0 = Bs + r * 32 + cc;
  unsigned short* lB1 = Bs + (64 + r) * 32 + cc;

  for (int k0 = 0; k0 < K; k0 += 32) {
    __syncthreads(); // previous iter's LDS reads complete
    gl_lds16(ga0 + k0, lA0);
    gl_lds16(ga1 + k0, lA1);
    gl_lds16(gb0 + k0, lB0);
    gl_lds16(gb1 + k0, lB1);
    __syncthreads(); // loads landed (vmcnt drained before barrier)
    bfv8 af[4], bfr[4];
#pragma unroll
    for (int i = 0; i < 4; ++i) {
      af[i]  = *(const bfv8*)(As + (wm + i * 16 + l15) * 32 + lk);
      bfr[i] = *(const bfv8*)(Bs + (wn + i * 16 + l15) * 32 + lk);
    }
#pragma unroll
    for (int i = 0; i < 4; ++i)
#pragma unroll
      for (int j = 0; j < 4; ++j) acc[i][j] = mfma16(af[i], bfr[j], acc[i][j]);
  }

#pragma unroll
  for (int j = 0; j < 4; ++j) {
    int col = nt * 128 + wn + j * 16 + l15;
    float bv = bias[col];
#pragma unroll
    for (int i = 0; i < 4; ++i) {
      int row0 = mt * 128 + wm + i * 16 + (lane >> 4) * 4;
#pragma unroll
      for (int q = 0; q < 4; ++q) {
        float v = acc[i][j][q] + bv;
        if (out_f32) ((float*)C)[(size_t)(row0 + q) * N + col] = v;
        else ((unsigned short*)C)[(size_t)(row0 + q) * N + col] = f2bf(v);
      }
    }
  }
}

// ---------------------------------------------------------------------------
// Persistent fused GRU scan. Grid = 256 WGs (1/CU, forced by 96KB LDS):
//   bid = dir*128 + mg*64 + utile.  WG owns 64 batch rows x 16 u-cols, 1 dir.
// Wh slice lives in LDS as Wl[gate][k/8][u][8] (B-fragment = 16B contiguous).
// f32 master h state in 4 VGPRs/lane.  h mirror (bf16) double-buffered:
// step s reads hb[(s&1)^1], writes hb[s&1]; per-step 64-WG group barrier.
// ---------------------------------------------------------------------------
__global__ __launch_bounds__(256) void k_scan(const unsigned short* __restrict__ XP,
                                              const unsigned short* __restrict__ WhT,
                                              const float* __restrict__ biasH,
                                              const int* __restrict__ tokens,
                                              unsigned short* __restrict__ hb0,
                                              unsigned short* __restrict__ hb1,
                                              float* __restrict__ out,
                                              unsigned int* __restrict__ bar) {
  __shared__ unsigned short Wl[3 * 128 * 16 * 8]; // 96 KB
  const int bid = blockIdx.x;
  const int dir = bid >> 7;
  const int mg  = (bid >> 6) & 1;
  const int ut  = bid & 63;
  const int u0 = ut * 16, m0 = mg * 64;
  const int grp = bid >> 6; // 4 groups of 64 WGs

  // stage Wh slice -> LDS (once)
  for (int c = threadIdx.x; c < 6144; c += 256) {
    const int g  = c >> 11;         // gate
    const int kb = (c >> 4) & 127;  // k-block of 8
    const int uu = c & 15;
    *(uint4*)(Wl + (((g << 7) | kb) * 16 + uu) * 8) =
        *(const uint4*)(WhT + (((size_t)(dir * N3U + (g << 10) + u0 + uu)) << 10) + (kb << 3));
  }

  const int lane = threadIdx.x & 63, wid = threadIdx.x >> 6;
  const int l15 = lane & 15, hi = lane >> 4;
  const size_t aoff = ((size_t)(m0 + wid * 16 + l15) << 11) + (dir << 10) + (hi << 3);
  const int u = u0 + l15;
  const float bz  = biasH[dir * N3U + u];
  const float brg = biasH[dir * N3U + 1024 + u];
  const float bhg = biasH[dir * N3U + 2048 + u];
  const int ob = m0 + wid * 16 + (hi << 2); // this lane's 4 output rows: ob..ob+3
  const size_t woff = (dir << 10) + u;

  float hreg[4] = {0.f, 0.f, 0.f, 0.f}; // f32 master state (private to this WG)
  __syncthreads();

  for (int s = 0; s < T_SEQ; ++s) {
    const int t = dir ? (T_SEQ - 1 - s) : s;
    const unsigned short* hrd = (s & 1) ? hb0 : hb1; // h_{s-1}
    unsigned short* hwr       = (s & 1) ? hb1 : hb0; // h_s

    // hoist XP + token loads for this step (hide latency under MFMAs)
    float xz[4], xr[4], xh[4]; int tok[4];
#pragma unroll
    for (int q = 0; q < 4; ++q) {
      const size_t xpo = ((size_t)((ob + q) * T_SEQ + t)) * N6U + dir * N3U + u;
      xz[q] = bf2f(XP[xpo]);
      xr[q] = bf2f(XP[xpo + 1024]);
      xh[q] = bf2f(XP[xpo + 2048]);
      tok[q] = tokens[(ob + q) * T_SEQ + t];
    }

    const unsigned short* ap = hrd + aoff;
    f32x4 az0 = {0.f,0.f,0.f,0.f}, az1 = az0, ar0 = az0, ar1 = az0, ah0 = az0, ah1 = az0;
#pragma unroll 4
    for (int ks = 0; ks < 16; ++ks) { // 64 k-elements per iter (2 k-splits)
      bfv8 a0 = *(const bfv8*)(ap + (ks << 6));
      bfv8 a1 = *(const bfv8*)(ap + (ks << 6) + 32);
      const unsigned short* wp = Wl + (((ks << 3) + hi) * 16 + l15) * 8;
      bfv8 wz0 = *(const bfv8*)(wp);
      bfv8 wr0 = *(const bfv8*)(wp + (1 << 14));
      bfv8 wh0 = *(const bfv8*)(wp + (2 << 14));
      bfv8 wz1 = *(const bfv8*)(wp + 512);            // kb+4
      bfv8 wr1 = *(const bfv8*)(wp + (1 << 14) + 512);
      bfv8 wh1 = *(const bfv8*)(wp + (2 << 14) + 512);
      az0 = mfma16(a0, wz0, az0); ar0 = mfma16(a0, wr0, ar0); ah0 = mfma16(a0, wh0, ah0);
      az1 = mfma16(a1, wz1, az1); ar1 = mfma16(a1, wr1, ar1); ah1 = mfma16(a1, wh1, ah1);
    }
    f32x4 az = az0 + az1, ar = ar0 + ar1, ah = ah0 + ah1;

#pragma unroll
    for (int q = 0; q < 4; ++q) {
      const float z  = 1.f / (1.f + __expf(-(xz[q] + az[q] + bz)));
      const float r  = 1.f / (1.f + __expf(-(xr[q] + ar[q] + brg)));
      const float hh = tanhf(xh[q] + r * (ah[q] + bhg));
      float hn = z * hreg[q] + (1.f - z) * hh;
      if (tok[q] == 0) hn = hreg[q]; // masked step carries state
      hreg[q] = hn;
      hwr[((size_t)(ob + q) << 11) + woff] = f2bf(hn);
      __builtin_nontemporal_store(hn, out + ((size_t)((ob + q) * T_SEQ + t) << 11) + woff);
    }

    if (s + 1 < T_SEQ) {
      __syncthreads(); // drains each wave's vmcnt -> all h stores are in L2
      if (threadIdx.x == 0) {
        // release: flush this XCD's L2 to the coherent point once
        __builtin_amdgcn_fence(__ATOMIC_RELEASE, "agent");
        __hip_atomic_fetch_add(&bar[grp], 1u, __ATOMIC_RELAXED, __HIP_MEMORY_SCOPE_AGENT);
        const unsigned tgt = (unsigned)(64 * (s + 1)); // monotonic: no reset race
        // RELAXED poll: no cache-maintenance per iteration
        while (__hip_atomic_load(&bar[grp], __ATOMIC_RELAXED, __HIP_MEMORY_SCOPE_AGENT) < tgt)
          __builtin_amdgcn_s_sleep(4);
        // acquire: one invalidate so normal loads see fresh h
        __builtin_amdgcn_fence(__ATOMIC_ACQUIRE, "agent");
      }
      __syncthreads();
    }
  }
}

extern "C" void kernel_launch(void* const* d_in, const int* in_sizes, int n_in,
                              void* d_out, int out_size, void* d_ws, size_t ws_size,
                              hipStream_t stream) {
  const int* tokens = (const int*)d_in[0];
  const float* emb  = (const float*)d_in[1];
  const float* Wx_f = (const float*)d_in[2];
  const float* Wh_f = (const float*)d_in[3];
  const float* b_f  = (const float*)d_in[4];
  const float* Wx_b = (const float*)d_in[5];
  const float* Wh_b = (const float*)d_in[6];
  const float* b_b  = (const float*)d_in[7];
  const float* fc_W = (const float*)d_in[8];
  const float* fc_b = (const float*)d_in[9];
  float* out = (float*)d_out;

  // workspace layout (~430 MB)
  char* w = (char*)d_ws;
  unsigned short* XP  = (unsigned short*)w; w += (size_t)NROWS * N6U * 2;   // 384 MiB
  unsigned short* Xbf = (unsigned short*)w; w += (size_t)NROWS * EMB_D * 2; // 32 MiB
  unsigned short* WxT = (unsigned short*)w; w += (size_t)N6U * EMB_D * 2;   // 6 MiB
  unsigned short* WhT = (unsigned short*)w; w += (size_t)N6U * UNITS * 2;   // 12 MiB
  unsigned short* fcWT = (unsigned short*)w; w += (size_t)UNITS * 2048 * 2; // 4 MiB
  unsigned short* hb0 = (unsigned short*)w; w += (size_t)BATCH * 2048 * 2;  // 0.5 MiB
  unsigned short* hb1 = (unsigned short*)w; w += (size_t)BATCH * 2048 * 2;  // 0.5 MiB
  float* biasX = (float*)w; w += N6U * 4;
  float* biasH = (float*)w; w += N6U * 4;
  unsigned int* bar = (unsigned int*)w; w += 4 * sizeof(unsigned int);

  (void)hipMemsetAsync((void*)hb0, 0, (size_t)BATCH * 2048 * 2 * 2, stream); // hb0+hb1
  (void)hipMemsetAsync((void*)bar, 0, 4 * sizeof(unsigned int), stream);

  // weight prep (f32 -> bf16, [N][K] layouts)
  k_transpose<<<dim3(EMB_D / 32, N3U / 32), 256, 0, stream>>>(Wx_f, WxT, EMB_D, N3U);
  k_transpose<<<dim3(EMB_D / 32, N3U / 32), 256, 0, stream>>>(Wx_b, WxT + (size_t)N3U * EMB_D, EMB_D, N3U);
  k_transpose<<<dim3(UNITS / 32, N3U / 32), 256, 0, stream>>>(Wh_f, WhT, UNITS, N3U);
  k_transpose<<<dim3(UNITS / 32, N3U / 32), 256, 0, stream>>>(Wh_b, WhT + (size_t)N3U * UNITS, UNITS, N3U);
  k_transpose<<<dim3(2048 / 32, 1024 / 32), 256, 0, stream>>>(fc_W, fcWT, 2048, 1024);
  k_bias<<<24, 256, 0, stream>>>(b_f, b_b, biasX, biasH);
  k_gather<<<(NROWS * 128) / 256, 256, 0, stream>>>(tokens, emb, Xbf);

  // input projections, both dirs: XP[32768][6144] bf16
  k_gemm<<<dim3(NROWS / 128, N6U / 128), 256, 0, stream>>>(Xbf, WxT, biasX, XP, NROWS, N6U, EMB_D, 0);

  // fused persistent bidirectional scan (256 steps inside one kernel)
  k_scan<<<256, 256, 0, stream>>>(XP, WhT, biasH, tokens, hb0, hb1, out, bar);

  // hidden = [h_f|h_b] @ fc_W + fc_b (final state is in hb1: step 255 is odd)
  k_gemm<<<dim3(1, 8), 256, 0, stream>>>(hb1, fcWT, fc_b, out + (size_t)NROWS * 2048, BATCH, UNITS, 2048, 1);
}

// Round 6
// 2835.955 us; speedup vs baseline: 6.7517x; 2.0687x over previous
//
#include <hip/hip_runtime.h>

// ---------------------------------------------------------------------------
// Bidirectional GRU encoder (Keras v2, reset_after=True, mask_zero)
// Round 5: barrier de-contention.
//  - bar counters: 4 groups x 8 subs, each on own 256B line (was: 4 uints on
//    ONE cacheline -> ~256 serialized IF-RMWs/step ~= 16us/step).
//  - h mirror writes: agent-scope relaxed atomic u64 (sc-bypass, write-through
//    to IF) via 2KB LDS bounce -> release fence (buffer_wbl2) removed.
//  - h reads stay cached; single acquire fence (buffer_inv) by wave0 after
//    poll (L1 per-CU covers the WG; L2 per-XCD).
// ---------------------------------------------------------------------------

#define T_SEQ 256
#define BATCH 128
#define EMB_D 512
#define UNITS 1024
#define NROWS (BATCH * T_SEQ) /* 32768 */
#define N3U 3072
#define N6U 6144

typedef __attribute__((ext_vector_type(8))) __bf16 bfv8;
typedef __attribute__((ext_vector_type(4))) float f32x4;

__device__ inline unsigned short f2bf(float f) {
  union { float f; unsigned int u; } x; x.f = f;
  unsigned int u = x.u;
  unsigned int r = (u + 0x7fffu + ((u >> 16) & 1u)) >> 16; // RNE
  return (unsigned short)r;
}
__device__ inline float bf2f(unsigned short h) {
  union { unsigned int u; float f; } x; x.u = ((unsigned int)h) << 16;
  return x.f;
}
__device__ inline f32x4 mfma16(bfv8 a, bfv8 b, f32x4 c) {
  return __builtin_amdgcn_mfma_f32_16x16x32_bf16(a, b, c, 0, 0, 0);
}
__device__ inline void gl_lds16(const unsigned short* g, unsigned short* l) {
  __builtin_amdgcn_global_load_lds(
      (const __attribute__((address_space(1))) void*)g,
      (__attribute__((address_space(3))) void*)l, 16, 0, 0);
}

// dst[N][K] (bf16) = src[K][N] (f32), 32x32 LDS-tiled transpose
__global__ __launch_bounds__(256) void k_transpose(const float* __restrict__ src,
                                                   unsigned short* __restrict__ dst,
                                                   int K, int N) {
  __shared__ float tile[32][33];
  int k0 = blockIdx.x * 32, n0 = blockIdx.y * 32;
  int tx = threadIdx.x & 31, ty = threadIdx.x >> 5;
#pragma unroll
  for (int i = 0; i < 4; ++i)
    tile[ty + i * 8][tx] = src[(size_t)(k0 + ty + i * 8) * N + n0 + tx];
  __syncthreads();
#pragma unroll
  for (int i = 0; i < 4; ++i)
    dst[(size_t)(n0 + ty + i * 8) * K + k0 + tx] = f2bf(tile[tx][ty + i * 8]);
}

// Xbf[32768][512] bf16 = emb[tokens[row]]
__global__ __launch_bounds__(256) void k_gather(const int* __restrict__ tokens,
                                                const float* __restrict__ emb,
                                                unsigned short* __restrict__ Xbf) {
  int idx = blockIdx.x * 256 + threadIdx.x; // one float4 per thread
  int row = idx >> 7;
  int c4 = (idx & 127) * 4;
  int tok = tokens[row];
  float4 v = *(const float4*)(emb + (size_t)tok * EMB_D + c4);
  ushort4 p;
  p.x = f2bf(v.x); p.y = f2bf(v.y); p.z = f2bf(v.z); p.w = f2bf(v.w);
  *(ushort4*)(Xbf + (size_t)row * EMB_D + c4) = p;
}

// biasX[6144] = [b_f[0] | b_b[0]],  biasH[6144] = [b_f[1] | b_b[1]]
__global__ __launch_bounds__(256) void k_bias(const float* __restrict__ bf_,
                                              const float* __restrict__ bb_,
                                              float* __restrict__ biasX,
                                              float* __restrict__ biasH) {
  int i = blockIdx.x * 256 + threadIdx.x;
  if (i >= N6U) return;
  if (i < N3U) { biasX[i] = bf_[i];        biasH[i] = bf_[N3U + i]; }
  else         { biasX[i] = bb_[i - N3U];  biasH[i] = bb_[i]; }
}

// C[M][N] = A[M][K](bf16) @ BT[N][K](bf16)^T + bias[N]
// 128x128 tile, 4 waves, BK=32, global_load_lds(16B) staging (m97 structure).
__global__ __launch_bounds__(256) void k_gemm(const unsigned short* __restrict__ A,
                                              const unsigned short* __restrict__ BT,
                                              const float* __restrict__ bias,
                                              void* __restrict__ C,
                                              int M, int N, int K, int out_f32) {
  __shared__ unsigned short As[128 * 32];
  __shared__ unsigned short Bs[128 * 32];
  const int mt = blockIdx.x, nt = blockIdx.y;
  const int tid = threadIdx.x;
  const int wid = tid >> 6, lane = tid & 63;
  const int wm = (wid >> 1) * 64, wn = (wid & 1) * 64;
  const int l15 = lane & 15, lk = (lane >> 4) * 8;

  f32x4 acc[4][4];
#pragma unroll
  for (int i = 0; i < 4; ++i)
#pragma unroll
    for (int j = 0; j < 4; ++j) acc[i][j] = (f32x4){0.f, 0.f, 0.f, 0.f};

  const int r = tid >> 2;          // staging row 0..63
  const int cc = (tid & 3) * 8;    // staging col (elements)
  const unsigned short* ga0 = A + (size_t)(mt * 128 + r) * K + cc;
  const unsigned short* ga1 = ga0 + (size_t)64 * K;
  const unsigned short* gb0 = BT + (size_t)(nt * 128 + r) * K + cc;
  const unsigned short* gb1 = gb0 + (size_t)64 * K;
  unsigned short* lA0 = As + r * 32 + cc;        // byte off = tid*16, wave-linear
  unsigned short* lA1 = As + (64 + r) * 32 + cc;
  unsigned short* lB0 = Bs + r * 32 + cc;
  unsigned short* lB1 = Bs + (64 + r) * 32 + cc;

  for (int k0 = 0; k0 < K; k0 += 32) {
    __syncthreads(); // previous iter's LDS reads complete
    gl_lds16(ga0 + k0, lA0);
    gl_lds16(ga1 + k0, lA1);
    gl_lds16(gb0 + k0, lB0);
    gl_lds16(gb1 + k0, lB1);
    __syncthreads(); // loads landed (vmcnt drained before barrier)
    bfv8 af[4], bfr[4];
#pragma unroll
    for (int i = 0; i < 4; ++i) {
      af[i]  = *(const bfv8*)(As + (wm + i * 16 + l15) * 32 + lk);
      bfr[i] = *(const bfv8*)(Bs + (wn + i * 16 + l15) * 32 + lk);
    }
#pragma unroll
    for (int i = 0; i < 4; ++i)
#pragma unroll
      for (int j = 0; j < 4; ++j) acc[i][j] = mfma16(af[i], bfr[j], acc[i][j]);
  }

#pragma unroll
  for (int j = 0; j < 4; ++j) {
    int col = nt * 128 + wn + j * 16 + l15;
    float bv = bias[col];
#pragma unroll
    for (int i = 0; i < 4; ++i) {
      int row0 = mt * 128 + wm + i * 16 + (lane >> 4) * 4;
#pragma unroll
      for (int q = 0; q < 4; ++q) {
        float v = acc[i][j][q] + bv;
        if (out_f32) ((float*)C)[(size_t)(row0 + q) * N + col] = v;
        else ((unsigned short*)C)[(size_t)(row0 + q) * N + col] = f2bf(v);
      }
    }
  }
}

// ---------------------------------------------------------------------------
// Persistent fused GRU scan. Grid = 256 WGs (1/CU, forced by 96KB LDS):
//   bid = dir*128 + mg*64 + utile.  WG owns 64 batch rows x 16 u-cols, 1 dir.
// Wh slice in LDS as Wl[gate][k/8][u][8]; f32 master h state in VGPRs.
// h mirror double-buffered; writes = coherent u64 atomic stores (IF-visible,
// no wbl2); reads = cached loads + one buffer_inv per step after the poll.
// Barrier: 8 padded sub-counters per 64-WG group; lanes 0-7 poll in parallel.
// ---------------------------------------------------------------------------
__global__ __launch_bounds__(256) void k_scan(const unsigned short* __restrict__ XP,
                                              const unsigned short* __restrict__ WhT,
                                              const float* __restrict__ biasH,
                                              const int* __restrict__ tokens,
                                              unsigned short* __restrict__ hb0,
                                              unsigned short* __restrict__ hb1,
                                              float* __restrict__ out,
                                              unsigned int* __restrict__ bar) {
  __shared__ unsigned short Wl[3 * 128 * 16 * 8]; // 96 KB
  __shared__ unsigned short bounce[64][16];       // 2 KB h_new re-layout tile
  const int bid = blockIdx.x;
  const int dir = bid >> 7;
  const int mg  = (bid >> 6) & 1;
  const int ut  = bid & 63;
  const int u0 = ut * 16, m0 = mg * 64;
  const int grp = bid >> 6;     // 4 groups of 64 WGs
  const int sub = bid & 7;      // 8 WGs per sub-counter

  // stage Wh slice -> LDS (once)
  for (int c = threadIdx.x; c < 6144; c += 256) {
    const int g  = c >> 11;         // gate
    const int kb = (c >> 4) & 127;  // k-block of 8
    const int uu = c & 15;
    *(uint4*)(Wl + (((g << 7) | kb) * 16 + uu) * 8) =
        *(const uint4*)(WhT + (((size_t)(dir * N3U + (g << 10) + u0 + uu)) << 10) + (kb << 3));
  }

  const int lane = threadIdx.x & 63, wid = threadIdx.x >> 6;
  const int l15 = lane & 15, hi = lane >> 4;
  const size_t aoff = ((size_t)(m0 + wid * 16 + l15) << 11) + (dir << 10) + (hi << 3);
  const int u = u0 + l15;
  const float bz  = biasH[dir * N3U + u];
  const float brg = biasH[dir * N3U + 1024 + u];
  const float bhg = biasH[dir * N3U + 2048 + u];
  const int ob = m0 + wid * 16 + (hi << 2); // this lane's 4 output rows: ob..ob+3
  const int rb = wid * 16 + (hi << 2);      // row within WG tile
  const size_t woff = (dir << 10) + u;
  // this thread's coherent-store slot: u64 unit (row, 4 u-cols)
  const int sr = threadIdx.x >> 2, sc4 = (threadIdx.x & 3) << 2;
  const size_t soff = ((size_t)(m0 + sr) << 11) + (dir << 10) + u0 + sc4;

  float hreg[4] = {0.f, 0.f, 0.f, 0.f}; // f32 master state (private to this WG)
  __syncthreads();

  for (int s = 0; s < T_SEQ; ++s) {
    const int t = dir ? (T_SEQ - 1 - s) : s;
    const unsigned short* hrd = (s & 1) ? hb0 : hb1; // h_{s-1}
    unsigned short* hwr       = (s & 1) ? hb1 : hb0; // h_s

    // hoist XP + token loads for this step (hide latency under MFMAs)
    float xz[4], xr[4], xh[4]; int tok[4];
#pragma unroll
    for (int q = 0; q < 4; ++q) {
      const size_t xpo = ((size_t)((ob + q) * T_SEQ + t)) * N6U + dir * N3U + u;
      xz[q] = bf2f(XP[xpo]);
      xr[q] = bf2f(XP[xpo + 1024]);
      xh[q] = bf2f(XP[xpo + 2048]);
      tok[q] = tokens[(ob + q) * T_SEQ + t];
    }

    const unsigned short* ap = hrd + aoff;
    f32x4 az0 = {0.f,0.f,0.f,0.f}, az1 = az0, ar0 = az0, ar1 = az0, ah0 = az0, ah1 = az0;
#pragma unroll 4
    for (int ks = 0; ks < 16; ++ks) { // 64 k-elements per iter (2 k-splits)
      bfv8 a0 = *(const bfv8*)(ap + (ks << 6));
      bfv8 a1 = *(const bfv8*)(ap + (ks << 6) + 32);
      const unsigned short* wp = Wl + (((ks << 3) + hi) * 16 + l15) * 8;
      bfv8 wz0 = *(const bfv8*)(wp);
      bfv8 wr0 = *(const bfv8*)(wp + (1 << 14));
      bfv8 wh0 = *(const bfv8*)(wp + (2 << 14));
      bfv8 wz1 = *(const bfv8*)(wp + 512);            // kb+4
      bfv8 wr1 = *(const bfv8*)(wp + (1 << 14) + 512);
      bfv8 wh1 = *(const bfv8*)(wp + (2 << 14) + 512);
      az0 = mfma16(a0, wz0, az0); ar0 = mfma16(a0, wr0, ar0); ah0 = mfma16(a0, wh0, ah0);
      az1 = mfma16(a1, wz1, az1); ar1 = mfma16(a1, wr1, ar1); ah1 = mfma16(a1, wh1, ah1);
    }
    f32x4 az = az0 + az1, ar = ar0 + ar1, ah = ah0 + ah1;

#pragma unroll
    for (int q = 0; q < 4; ++q) {
      const float z  = 1.f / (1.f + __expf(-(xz[q] + az[q] + bz)));
      const float r  = 1.f / (1.f + __expf(-(xr[q] + ar[q] + brg)));
      const float hh = tanhf(xh[q] + r * (ah[q] + bhg));
      float hn = z * hreg[q] + (1.f - z) * hh;
      if (tok[q] == 0) hn = hreg[q]; // masked step carries state
      hreg[q] = hn;
      bounce[rb + q][l15] = f2bf(hn); // LDS re-layout for coherent u64 store
      __builtin_nontemporal_store(hn, out + ((size_t)((ob + q) * T_SEQ + t) << 11) + woff);
    }

    __syncthreads(); // bounce tile complete
    {
      unsigned long long v = *(const unsigned long long*)&bounce[sr][sc4];
      // write-through to IF (sc-bypass): visible device-wide once vmcnt acks
      __hip_atomic_store((unsigned long long*)(hwr + soff), v,
                         __ATOMIC_RELAXED, __HIP_MEMORY_SCOPE_AGENT);
    }

    if (s + 1 < T_SEQ) {
      __syncthreads(); // drains vmcnt: all coherent h stores are at IF
      if (threadIdx.x == 0)
        __hip_atomic_fetch_add(&bar[((grp << 3) | sub) << 6], 1u,
                               __ATOMIC_RELAXED, __HIP_MEMORY_SCOPE_AGENT);
      if (threadIdx.x < 8) {
        const unsigned tgt = 8u * (unsigned)(s + 1); // monotonic: no reset race
        unsigned int* p = &bar[((grp << 3) | (int)threadIdx.x) << 6];
        while (__hip_atomic_load(p, __ATOMIC_RELAXED, __HIP_MEMORY_SCOPE_AGENT) < tgt)
          __builtin_amdgcn_s_sleep(2);
        // acquire: one buffer_inv -> CU L1 + XCD L2 drop stale h lines
        __builtin_amdgcn_fence(__ATOMIC_ACQUIRE, "agent");
      }
      __syncthreads();
    }
  }
}

extern "C" void kernel_launch(void* const* d_in, const int* in_sizes, int n_in,
                              void* d_out, int out_size, void* d_ws, size_t ws_size,
                              hipStream_t stream) {
  const int* tokens = (const int*)d_in[0];
  const float* emb  = (const float*)d_in[1];
  const float* Wx_f = (const float*)d_in[2];
  const float* Wh_f = (const float*)d_in[3];
  const float* b_f  = (const float*)d_in[4];
  const float* Wx_b = (const float*)d_in[5];
  const float* Wh_b = (const float*)d_in[6];
  const float* b_b  = (const float*)d_in[7];
  const float* fc_W = (const float*)d_in[8];
  const float* fc_b = (const float*)d_in[9];
  float* out = (float*)d_out;

  // workspace layout (~430 MB)
  char* w = (char*)d_ws;
  unsigned short* XP  = (unsigned short*)w; w += (size_t)NROWS * N6U * 2;   // 384 MiB
  unsigned short* Xbf = (unsigned short*)w; w += (size_t)NROWS * EMB_D * 2; // 32 MiB
  unsigned short* WxT = (unsigned short*)w; w += (size_t)N6U * EMB_D * 2;   // 6 MiB
  unsigned short* WhT = (unsigned short*)w; w += (size_t)N6U * UNITS * 2;   // 12 MiB
  unsigned short* fcWT = (unsigned short*)w; w += (size_t)UNITS * 2048 * 2; // 4 MiB
  unsigned short* hb0 = (unsigned short*)w; w += (size_t)BATCH * 2048 * 2;  // 0.5 MiB
  unsigned short* hb1 = (unsigned short*)w; w += (size_t)BATCH * 2048 * 2;  // 0.5 MiB
  float* biasX = (float*)w; w += N6U * 4;
  float* biasH = (float*)w; w += N6U * 4;
  unsigned int* bar = (unsigned int*)w; w += 2048 * sizeof(unsigned int);   // 8 KB padded

  (void)hipMemsetAsync((void*)hb0, 0, (size_t)BATCH * 2048 * 2 * 2, stream); // hb0+hb1
  (void)hipMemsetAsync((void*)bar, 0, 2048 * sizeof(unsigned int), stream);

  // weight prep (f32 -> bf16, [N][K] layouts)
  k_transpose<<<dim3(EMB_D / 32, N3U / 32), 256, 0, stream>>>(Wx_f, WxT, EMB_D, N3U);
  k_transpose<<<dim3(EMB_D / 32, N3U / 32), 256, 0, stream>>>(Wx_b, WxT + (size_t)N3U * EMB_D, EMB_D, N3U);
  k_transpose<<<dim3(UNITS / 32, N3U / 32), 256, 0, stream>>>(Wh_f, WhT, UNITS, N3U);
  k_transpose<<<dim3(UNITS / 32, N3U / 32), 256, 0, stream>>>(Wh_b, WhT + (size_t)N3U * UNITS, UNITS, N3U);
  k_transpose<<<dim3(2048 / 32, 1024 / 32), 256, 0, stream>>>(fc_W, fcWT, 2048, 1024);
  k_bias<<<24, 256, 0, stream>>>(b_f, b_b, biasX, biasH);
  k_gather<<<(NROWS * 128) / 256, 256, 0, stream>>>(tokens, emb, Xbf);

  // input projections, both dirs: XP[32768][6144] bf16
  k_gemm<<<dim3(NROWS / 128, N6U / 128), 256, 0, stream>>>(Xbf, WxT, biasX, XP, NROWS, N6U, EMB_D, 0);

  // fused persistent bidirectional scan (256 steps inside one kernel)
  k_scan<<<256, 256, 0, stream>>>(XP, WhT, biasH, tokens, hb0, hb1, out, bar);

  // hidden = [h_f|h_b] @ fc_W + fc_b (final state is in hb1: step 255 is odd)
  k_gemm<<<dim3(1, 8), 256, 0, stream>>>(hb1, fcWT, fc_b, out + (size_t)NROWS * 2048, BATCH, UNITS, 2048, 1);
}